// Round 4
// baseline (369.815 us; speedup 1.0000x reference)
//
#include <hip/hip_runtime.h>
#include <math.h>

#define C 128
#define NSP 4096  // H*W
#define LOG2E 1.4426950408889634f

typedef __attribute__((ext_vector_type(8))) short short8;
typedef __attribute__((ext_vector_type(4))) float f32x4;

static __device__ __forceinline__ unsigned short f2bf(float f) {
    union { float f; unsigned u; } a; a.f = f;
    unsigned r = a.u + 0x7fffu + ((a.u >> 16) & 1u);
    return (unsigned short)(r >> 16);
}

static __device__ __forceinline__ float bf2f(unsigned short s) {
    union { unsigned u; float f; } a; a.u = (unsigned)s << 16;
    return a.f;
}

// pack two f32 -> bf16x2 (round-half-up) in ~3 VALU ops
static __device__ __forceinline__ unsigned pkbf(float a, float b) {
    union { float f; unsigned u; } ua, ub; ua.f = a; ub.f = b;
    return __builtin_amdgcn_perm(ub.u + 0x8000u, ua.u + 0x8000u, 0x07060302u);
}

static __device__ __forceinline__ float ex2(float x) {
#if __has_builtin(__builtin_amdgcn_exp2f)
    return __builtin_amdgcn_exp2f(x);
#else
    return exp2f(x);
#endif
}

static __device__ __forceinline__ f32x4 mfma16(short8 a, short8 b, f32x4 c) {
    // D[row=quad*4+reg][col=lane&15]; A[row=lane&15][k=quad*8+j]; B[k=quad*8+j][col=lane&15]
    return __builtin_amdgcn_mfma_f32_16x16x32_bf16(a, b, c, 0, 0, 0);
}

// ---- staging helpers ----
static __device__ __forceinline__ void stage_w(const float* __restrict__ W,
                                               unsigned short* __restrict__ Wl, int t,
                                               float scale) {
#pragma unroll
    for (int i = 0; i < 16; i++) {
        int idx = i * 256 + t;
        int o = idx >> 5, c4 = (idx & 31) << 2;
        float4 v = *reinterpret_cast<const float4*>(W + o * C + c4);
        uint2 u;
        u.x = pkbf(v.x * scale, v.y * scale);
        u.y = pkbf(v.z * scale, v.w * scale);
        *reinterpret_cast<uint2*>(&Wl[o * 136 + c4]) = u;
    }
}

static __device__ __forceinline__ void stage_in(const float* __restrict__ In, int n0,
                                                unsigned short* __restrict__ Il, int t) {
#pragma unroll
    for (int i = 0; i < 8; i++) {
        int idx = i * 256 + t;
        int c = idx >> 4, n4 = (idx & 15) << 2;
        float4 v = *reinterpret_cast<const float4*>(In + (size_t)c * NSP + n0 + n4);
        Il[(n4 + 0) * 136 + c] = f2bf(v.x);
        Il[(n4 + 1) * 136 + c] = f2bf(v.y);
        Il[(n4 + 2) * 136 + c] = f2bf(v.z);
        Il[(n4 + 3) * 136 + c] = f2bf(v.w);
    }
}

// straight copy of [n][c] bf16 input into Il[n][c] (pad 136)
static __device__ __forceinline__ void stage_nc(const unsigned short* __restrict__ In, int n0,
                                                unsigned short* __restrict__ Il, int t) {
#pragma unroll
    for (int i = 0; i < 4; i++) {
        int idx = i * 256 + t;
        int n = idx >> 4, c8 = (idx & 15) << 3;
        uint4 v = *reinterpret_cast<const uint4*>(In + (size_t)(n0 + n) * C + c8);
        *reinterpret_cast<uint4*>(&Il[n * 136 + c8]) = v;
    }
}

// ======================= QKV projection =======================
// out = relu(W @ in + b).  Q,K stored [n][c] bf16 ; V stored [c][n] bf16.
// Q (kind 0) is pre-scaled by log2(e) so attention can use exp2 directly.
__global__ __launch_bounds__(256)
void qkv_kernel(const float* __restrict__ qs0, const float* __restrict__ qs1,
                const float* __restrict__ kv0, const float* __restrict__ kv1,
                const float* __restrict__ Wq, const float* __restrict__ Wk,
                const float* __restrict__ Wv,
                const float* __restrict__ bq, const float* __restrict__ bk,
                const float* __restrict__ bv,
                int layer_base,
                unsigned short* __restrict__ Qb, unsigned short* __restrict__ Kb,
                unsigned short* __restrict__ Vb)
{
    __shared__ __align__(16) unsigned short Wl[128 * 136];
    __shared__ __align__(16) unsigned short Il[64 * 136];
    const int t = threadIdx.x;
    const int ntile = blockIdx.x, kind = blockIdx.y, jb = blockIdx.z;
    const int job = jb >> 1, b = jb & 1, layer = layer_base + job;
    const float* src = (kind == 0) ? (job ? qs1 : qs0) : (job ? kv1 : kv0);
    const float* In = src + (size_t)b * C * NSP;
    const float* W = ((kind == 0) ? Wq : (kind == 1) ? Wk : Wv) + (size_t)layer * C * C;
    const float* bias = ((kind == 0) ? bq : (kind == 1) ? bk : bv) + layer * C;
    unsigned short* Out = ((kind == 0) ? Qb : (kind == 1) ? Kb : Vb) + (size_t)jb * NSP * C;
    const float scale = (kind == 0) ? LOG2E : 1.0f;
    const int n0 = ntile * 64;

    stage_w(W, Wl, t, scale);
    stage_in(In, n0, Il, t);
    __syncthreads();

    const int lane = t & 63, w = t >> 6, l15 = lane & 15, quad = lane >> 4;

    if (kind <= 1) {
        f32x4 acc[4][2];
#pragma unroll
        for (int nt = 0; nt < 4; nt++)
#pragma unroll
            for (int ot = 0; ot < 2; ot++)
#pragma unroll
                for (int r = 0; r < 4; r++) acc[nt][ot][r] = 0.0f;
#pragma unroll
        for (int ks = 0; ks < 4; ks++) {
            int co = ks * 32 + quad * 8;
            short8 b0 = *reinterpret_cast<const short8*>(&Wl[(w * 32 + l15) * 136 + co]);
            short8 b1 = *reinterpret_cast<const short8*>(&Wl[(w * 32 + 16 + l15) * 136 + co]);
#pragma unroll
            for (int nt = 0; nt < 4; nt++) {
                short8 a = *reinterpret_cast<const short8*>(&Il[(nt * 16 + l15) * 136 + co]);
                acc[nt][0] = mfma16(a, b0, acc[nt][0]);
                acc[nt][1] = mfma16(a, b1, acc[nt][1]);
            }
        }
        float bz0 = bias[w * 32 + l15] * scale;
        float bz1 = bias[w * 32 + 16 + l15] * scale;
#pragma unroll
        for (int nt = 0; nt < 4; nt++)
#pragma unroll
            for (int ot = 0; ot < 2; ot++)
#pragma unroll
                for (int r = 0; r < 4; r++) {
                    float v = fmaxf(acc[nt][ot][r] + (ot ? bz1 : bz0), 0.0f);
                    int n = n0 + nt * 16 + quad * 4 + r;
                    int o = w * 32 + ot * 16 + l15;
                    Out[(size_t)n * C + o] = f2bf(v);
                }
    } else {
        f32x4 acc[2][4];
#pragma unroll
        for (int ot = 0; ot < 2; ot++)
#pragma unroll
            for (int nt = 0; nt < 4; nt++)
#pragma unroll
                for (int r = 0; r < 4; r++) acc[ot][nt][r] = 0.0f;
#pragma unroll
        for (int ks = 0; ks < 4; ks++) {
            int co = ks * 32 + quad * 8;
            short8 a0 = *reinterpret_cast<const short8*>(&Wl[(w * 32 + l15) * 136 + co]);
            short8 a1 = *reinterpret_cast<const short8*>(&Wl[(w * 32 + 16 + l15) * 136 + co]);
#pragma unroll
            for (int nt = 0; nt < 4; nt++) {
                short8 bb = *reinterpret_cast<const short8*>(&Il[(nt * 16 + l15) * 136 + co]);
                acc[0][nt] = mfma16(a0, bb, acc[0][nt]);
                acc[1][nt] = mfma16(a1, bb, acc[1][nt]);
            }
        }
#pragma unroll
        for (int ot = 0; ot < 2; ot++)
#pragma unroll
            for (int r = 0; r < 4; r++) {
                int o = w * 32 + ot * 16 + quad * 4 + r;
                float bz = bias[o];
#pragma unroll
                for (int nt = 0; nt < 4; nt++) {
                    float v = fmaxf(acc[ot][nt][r] + bz, 0.0f);
                    Out[(size_t)o * NSP + n0 + nt * 16 + l15] = f2bf(v);
                }
            }
    }
}

// ======================= attention: barrier-free, K/V direct from global =======================
// S = Q.K >= 0 and bounded (ReLU'd inputs, unscaled softmax) -> no running max needed.
// P = exp2(S) with log2e folded into Q. Each wave owns 32 Q cols; K/V fragments are
// loaded straight from global (L1/L2-resident streams); the ONLY LDS use is the
// wave-private P layout round-trip and the wave-private epilogue transpose.
// Main loop has NO __syncthreads.
__global__ __launch_bounds__(256)
void attn_kernel(const unsigned short* __restrict__ Qb, const unsigned short* __restrict__ Kb,
                 const unsigned short* __restrict__ Vb, unsigned short* __restrict__ Op,
                 float* __restrict__ Lp, int iters)
{
    __shared__ __align__(16) unsigned short Pw[4 * 32 * 40];   // 10240 B per-wave [n][m]
    __shared__ __align__(16) unsigned short Oe[4 * 16 * 136];  // 17408 B per-wave epilogue
    const int t = threadIdx.x, lane = t & 63, w = t >> 6;
    const int l15 = lane & 15, quad = lane >> 4;
    unsigned short* Pm = &Pw[w * 1280];
    unsigned short* Ow = &Oe[w * 16 * 136];

    const int jb = blockIdx.y, kc = blockIdx.z;
    const int n0 = blockIdx.x * 128 + w * 32;
    const int m_begin = kc * iters * 32;
    const unsigned short* Q = Qb + (size_t)jb * NSP * C;
    const unsigned short* K = Kb + (size_t)jb * NSP * C;
    const unsigned short* V = Vb + (size_t)jb * NSP * C;  // [c][n]

    // Q fragments (B-operand), resident: [nt][ks]
    short8 qf[2][4];
#pragma unroll
    for (int nt = 0; nt < 2; nt++)
#pragma unroll
        for (int ks = 0; ks < 4; ks++)
            qf[nt][ks] = *reinterpret_cast<const short8*>(
                Q + (size_t)(n0 + nt * 16 + l15) * C + ks * 32 + quad * 8);

    f32x4 o_acc[8][2];
#pragma unroll
    for (int ct = 0; ct < 8; ct++)
#pragma unroll
        for (int nt = 0; nt < 2; nt++)
#pragma unroll
            for (int r = 0; r < 4; r++) o_acc[ct][nt][r] = 0.0f;
    float L[2] = {0.0f, 0.0f};

    // per-lane base pointers (advance by elements per iter)
    const unsigned short* Kp = K + (size_t)(m_begin + l15) * C + quad * 8;   // + mt*16*C + ks*32
    const unsigned short* Vp = V + (size_t)l15 * NSP + m_begin + quad * 8;   // + ct*16*NSP

    for (int blk = 0; blk < iters; blk++) {
        const unsigned short* Kblk = Kp + (size_t)blk * 32 * C;
        const unsigned short* Vblk = Vp + blk * 32;

        // ---- QK^T: S^T[m][n], A = K rows m, B = Q cols n ----
        f32x4 s[2][2];
#pragma unroll
        for (int mt = 0; mt < 2; mt++)
#pragma unroll
            for (int nt = 0; nt < 2; nt++)
#pragma unroll
                for (int r = 0; r < 4; r++) s[mt][nt][r] = 0.0f;
        short8 kf0[4], kf1[4];
#pragma unroll
        for (int ks = 0; ks < 4; ks++)
            kf0[ks] = *reinterpret_cast<const short8*>(Kblk + ks * 32);
#pragma unroll
        for (int ks = 0; ks < 4; ks++)
            kf1[ks] = *reinterpret_cast<const short8*>(Kblk + 16 * C + ks * 32);
#pragma unroll
        for (int ks = 0; ks < 4; ks++) {
            s[0][0] = mfma16(kf0[ks], qf[0][ks], s[0][0]);
            s[0][1] = mfma16(kf0[ks], qf[1][ks], s[0][1]);
            s[1][0] = mfma16(kf1[ks], qf[0][ks], s[1][0]);
            s[1][1] = mfma16(kf1[ks], qf[1][ks], s[1][1]);
        }

        // ---- V fragments (independent of S; overlap with exp/pack) ----
        short8 vf[8];
#pragma unroll
        for (int ct = 0; ct < 8; ct++)
            vf[ct] = *reinterpret_cast<const short8*>(Vblk + (size_t)ct * 16 * NSP);

        // ---- P = exp2(S), accumulate L, pack to wave-private LDS [n][m] ----
#pragma unroll
        for (int nt = 0; nt < 2; nt++) {
            float pv[2][4];
            float ls = 0.0f;
#pragma unroll
            for (int mt = 0; mt < 2; mt++)
#pragma unroll
                for (int r = 0; r < 4; r++) {
                    pv[mt][r] = ex2(s[mt][nt][r]);
                    ls += pv[mt][r];
                }
            L[nt] += ls;
#pragma unroll
            for (int mt = 0; mt < 2; mt++) {
                uint2 u;
                u.x = pkbf(pv[mt][0], pv[mt][1]);
                u.y = pkbf(pv[mt][2], pv[mt][3]);
                *reinterpret_cast<uint2*>(&Pm[(nt * 16 + l15) * 40 + mt * 16 + quad * 4]) = u;
            }
        }
        // ---- PV: O^T[c][n] += V[c][m] * P^T[m][n] ----
        short8 pf0 = *reinterpret_cast<const short8*>(&Pm[l15 * 40 + quad * 8]);
        short8 pf1 = *reinterpret_cast<const short8*>(&Pm[(16 + l15) * 40 + quad * 8]);
#pragma unroll
        for (int ct = 0; ct < 8; ct++) {
            o_acc[ct][0] = mfma16(vf[ct], pf0, o_acc[ct][0]);
            o_acc[ct][1] = mfma16(vf[ct], pf1, o_acc[ct][1]);
        }
    }

    // ---- epilogue: L reduce + coalesced partial-O store via wave-private LDS transpose ----
    const size_t kjb = (size_t)(kc * 4 + jb);
#pragma unroll
    for (int nt = 0; nt < 2; nt++) {
        float Lv = L[nt];
        Lv += __shfl_xor(Lv, 16);
        Lv += __shfl_xor(Lv, 32);
        if (quad == 0) Lp[kjb * NSP + n0 + nt * 16 + l15] = Lv;
    }
    unsigned short* Ob = Op + kjb * NSP * C;  // [n][c]
#pragma unroll
    for (int nt = 0; nt < 2; nt++) {
        // write o_acc frags: row n=l15 (16 rows), col c=ct*16+quad*4
#pragma unroll
        for (int ct = 0; ct < 8; ct++) {
            uint2 u;
            u.x = pkbf(o_acc[ct][nt][0], o_acc[ct][nt][1]);
            u.y = pkbf(o_acc[ct][nt][2], o_acc[ct][nt][3]);
            *reinterpret_cast<uint2*>(&Ow[l15 * 136 + ct * 16 + quad * 4]) = u;
        }
        // read back coalesced: 4 rows x 256B per store
#pragma unroll
        for (int i = 0; i < 4; i++) {
            int nl = i * 4 + quad;
            uint4 v = *reinterpret_cast<const uint4*>(&Ow[nl * 136 + l15 * 8]);
            *reinterpret_cast<uint4*>(Ob + (size_t)(n0 + nt * 16 + nl) * C + l15 * 8) = v;
        }
    }
}

// ======================= combine split-K partials (plain sums) =======================
// att[jb][n][c] (bf16, aliases Op k=0) = (sum_k Op_k) / (sum_k L_k)
__global__ __launch_bounds__(256)
void combine_kernel(unsigned short* __restrict__ Op, const float* __restrict__ Lp, int nks)
{
    int gid = blockIdx.x * 256 + threadIdx.x;
    int c8 = (gid & 15) << 3;
    int n  = (gid >> 4) & 4095;
    int jb = gid >> 16;
    float Ls = 0.0f;
    for (int k = 0; k < nks; k++) Ls += Lp[(size_t)(k * 4 + jb) * NSP + n];
    float o[8];
#pragma unroll
    for (int j = 0; j < 8; j++) o[j] = 0.0f;
    for (int k = 0; k < nks; k++) {
        union { uint4 v; unsigned short s[8]; } u;
        u.v = *reinterpret_cast<const uint4*>(Op + ((size_t)(k * 4 + jb) * NSP + n) * C + c8);
#pragma unroll
        for (int j = 0; j < 8; j++) o[j] += bf2f(u.s[j]);
    }
    float inv = 1.0f / Ls;
    uint4 r;
    r.x = pkbf(o[0] * inv, o[1] * inv);
    r.y = pkbf(o[2] * inv, o[3] * inv);
    r.z = pkbf(o[4] * inv, o[5] * inv);
    r.w = pkbf(o[6] * inv, o[7] * inv);
    *reinterpret_cast<uint4*>(Op + ((size_t)jb * NSP + n) * C + c8) = r;
}

// ======================= output projection + residual (pass 1) =======================
__global__ __launch_bounds__(256)
void proj_kernel(const unsigned short* __restrict__ att, const float* __restrict__ Wo,
                 const float* __restrict__ bo, int layer_base,
                 const float* __restrict__ res0, const float* __restrict__ res1,
                 float* __restrict__ out0, float* __restrict__ out1)
{
    __shared__ __align__(16) unsigned short Wl[128 * 136];
    __shared__ __align__(16) unsigned short Il[64 * 136];
    const int t = threadIdx.x;
    const int ntile = blockIdx.x, jb = blockIdx.y;
    const int job = jb >> 1, b = jb & 1, layer = layer_base + job;
    const unsigned short* In = att + (size_t)jb * NSP * C;  // [n][c]
    const float* bias = bo + layer * C;
    const float* res = (job ? res1 : res0) + (size_t)b * C * NSP;
    float* out = (job ? out1 : out0) + (size_t)b * C * NSP;
    const int n0 = ntile * 64;

    stage_w(Wo + (size_t)layer * C * C, Wl, t, 1.0f);
    stage_nc(In, n0, Il, t);
    __syncthreads();

    const int lane = t & 63, w = t >> 6, l15 = lane & 15, quad = lane >> 4;
    f32x4 acc[2][4];
#pragma unroll
    for (int ot = 0; ot < 2; ot++)
#pragma unroll
        for (int nt = 0; nt < 4; nt++)
#pragma unroll
            for (int r = 0; r < 4; r++) acc[ot][nt][r] = 0.0f;
#pragma unroll
    for (int ks = 0; ks < 4; ks++) {
        int co = ks * 32 + quad * 8;
        short8 a0 = *reinterpret_cast<const short8*>(&Wl[(w * 32 + l15) * 136 + co]);
        short8 a1 = *reinterpret_cast<const short8*>(&Wl[(w * 32 + 16 + l15) * 136 + co]);
#pragma unroll
        for (int nt = 0; nt < 4; nt++) {
            short8 bb = *reinterpret_cast<const short8*>(&Il[(nt * 16 + l15) * 136 + co]);
            acc[0][nt] = mfma16(a0, bb, acc[0][nt]);
            acc[1][nt] = mfma16(a1, bb, acc[1][nt]);
        }
    }
#pragma unroll
    for (int ot = 0; ot < 2; ot++)
#pragma unroll
        for (int r = 0; r < 4; r++) {
            int o = w * 32 + ot * 16 + quad * 4 + r;
            float bz = bias[o];
#pragma unroll
            for (int nt = 0; nt < 4; nt++) {
                int n = n0 + nt * 16 + l15;
                float v = fmaxf(acc[ot][nt][r] + bz, 0.0f) + res[(size_t)o * NSP + n];
                out[(size_t)o * NSP + n] = v;
            }
        }
}

// ======================= final: both jobs summed into d_out =======================
__global__ __launch_bounds__(256)
void final_kernel(const unsigned short* __restrict__ att, const float* __restrict__ Wo,
                  const float* __restrict__ bo,
                  const float* __restrict__ fuse0, const float* __restrict__ fuse1,
                  float* __restrict__ out)
{
    __shared__ __align__(16) unsigned short Wl[128 * 136];
    __shared__ __align__(16) unsigned short Il[64 * 136];
    const int t = threadIdx.x;
    const int ntile = blockIdx.x, b = blockIdx.y;
    const int n0 = ntile * 64;
    const int lane = t & 63, w = t >> 6, l15 = lane & 15, quad = lane >> 4;

    float tot[2][4][4];
#pragma unroll
    for (int ot = 0; ot < 2; ot++)
#pragma unroll
        for (int nt = 0; nt < 4; nt++)
#pragma unroll
            for (int r = 0; r < 4; r++) tot[ot][nt][r] = 0.0f;

    for (int j = 0; j < 2; j++) {
        if (j) __syncthreads();
        int layer = 2 + j;
        stage_w(Wo + (size_t)layer * C * C, Wl, t, 1.0f);
        stage_nc(att + (size_t)(j * 2 + b) * NSP * C, n0, Il, t);
        __syncthreads();

        f32x4 acc[2][4];
#pragma unroll
        for (int ot = 0; ot < 2; ot++)
#pragma unroll
            for (int nt = 0; nt < 4; nt++)
#pragma unroll
                for (int r = 0; r < 4; r++) acc[ot][nt][r] = 0.0f;
#pragma unroll
        for (int ks = 0; ks < 4; ks++) {
            int co = ks * 32 + quad * 8;
            short8 a0 = *reinterpret_cast<const short8*>(&Wl[(w * 32 + l15) * 136 + co]);
            short8 a1 = *reinterpret_cast<const short8*>(&Wl[(w * 32 + 16 + l15) * 136 + co]);
#pragma unroll
            for (int nt = 0; nt < 4; nt++) {
                short8 bb = *reinterpret_cast<const short8*>(&Il[(nt * 16 + l15) * 136 + co]);
                acc[0][nt] = mfma16(a0, bb, acc[0][nt]);
                acc[1][nt] = mfma16(a1, bb, acc[1][nt]);
            }
        }
        const float* bias = bo + layer * C;
        const float* fuse = (j ? fuse1 : fuse0) + (size_t)b * C * NSP;
#pragma unroll
        for (int ot = 0; ot < 2; ot++)
#pragma unroll
            for (int r = 0; r < 4; r++) {
                int o = w * 32 + ot * 16 + quad * 4 + r;
                float bz = bias[o];
#pragma unroll
                for (int nt = 0; nt < 4; nt++) {
                    int n = n0 + nt * 16 + l15;
                    tot[ot][nt][r] += fmaxf(acc[ot][nt][r] + bz, 0.0f) + fuse[(size_t)o * NSP + n];
                }
            }
    }
#pragma unroll
    for (int ot = 0; ot < 2; ot++)
#pragma unroll
        for (int r = 0; r < 4; r++) {
            int o = w * 32 + ot * 16 + quad * 4 + r;
#pragma unroll
            for (int nt = 0; nt < 4; nt++) {
                int n = n0 + nt * 16 + l15;
                out[(size_t)b * C * NSP + (size_t)o * NSP + n] = tot[ot][nt][r];
            }
        }
}

extern "C" void kernel_launch(void* const* d_in, const int* in_sizes, int n_in,
                              void* d_out, int out_size, void* d_ws, size_t ws_size,
                              hipStream_t stream)
{
    (void)in_sizes; (void)n_in; (void)out_size;
    const float* x  = (const float*)d_in[0];
    const float* y  = (const float*)d_in[1];
    const float* Wq = (const float*)d_in[2];
    const float* bq = (const float*)d_in[3];
    const float* Wk = (const float*)d_in[4];
    const float* bk = (const float*)d_in[5];
    const float* Wv = (const float*)d_in[6];
    const float* bv = (const float*)d_in[7];
    const float* Wo = (const float*)d_in[8];
    const float* bo = (const float*)d_in[9];
    float* out = (float*)d_out;
    char* ws = (char*)d_ws;

    // split-K factor from available workspace (constant per process)
    // need(ks) = 12M (QKV) + ks*4M (Op) + ks*64K (Lp) + 8M (fuse)
    int ks = (ws_size >= 55050240u) ? 8 : (ws_size >= 38010880u) ? 4 : 2;
    int iters = 128 / ks;

    unsigned short* Qb = (unsigned short*)(ws);               // 4 MB [jb][n][c]
    unsigned short* Kb = (unsigned short*)(ws + (4u << 20));  // 4 MB [jb][n][c]
    unsigned short* Vb = (unsigned short*)(ws + (8u << 20));  // 4 MB [jb][c][n]
    unsigned short* Op = (unsigned short*)(ws + (12u << 20)); // ks*4 MB [k][jb][n][c] bf16
    size_t op_bytes = (size_t)ks * 4 * NSP * C * 2;
    float* Lp = (float*)(ws + (12u << 20) + op_bytes);        // ks*64 KB [k*4+jb][n]
    float* fuse0 = Lp + (size_t)ks * 4 * NSP;                 // 4 MB [b][c][n] fp32
    float* fuse1 = fuse0 + (size_t)2 * C * NSP;               // 4 MB
    unsigned short* att = Op;  // combine output aliases partial k=0

    // pass 1: L0 (Q from x, KV from y), L1 (Q from y, KV from x)
    qkv_kernel<<<dim3(64, 3, 4), 256, 0, stream>>>(x, y, y, x, Wq, Wk, Wv, bq, bk, bv, 0,
                                                   Qb, Kb, Vb);
    attn_kernel<<<dim3(32, 4, ks), 256, 0, stream>>>(Qb, Kb, Vb, Op, Lp, iters);
    combine_kernel<<<dim3(1024), 256, 0, stream>>>(Op, Lp, ks);
    proj_kernel<<<dim3(64, 4), 256, 0, stream>>>(att, Wo, bo, 0, x, y, fuse0, fuse1);

    // pass 2: L2 (all from fuse_xy), L3 (all from fuse_yz)
    qkv_kernel<<<dim3(64, 3, 4), 256, 0, stream>>>(fuse0, fuse1, fuse0, fuse1, Wq, Wk, Wv,
                                                   bq, bk, bv, 2, Qb, Kb, Vb);
    attn_kernel<<<dim3(32, 4, ks), 256, 0, stream>>>(Qb, Kb, Vb, Op, Lp, iters);
    combine_kernel<<<dim3(1024), 256, 0, stream>>>(Op, Lp, ks);
    final_kernel<<<dim3(64, 2), 256, 0, stream>>>(att, Wo, bo, fuse0, fuse1, out);
}

// Round 5
// 321.783 us; speedup vs baseline: 1.1493x; 1.1493x over previous
//
#include <hip/hip_runtime.h>
#include <math.h>

#define C 128
#define NSP 4096  // H*W
#define LOG2E 1.4426950408889634f

typedef __attribute__((ext_vector_type(8))) short short8;
typedef __attribute__((ext_vector_type(4))) float f32x4;

static __device__ __forceinline__ unsigned short f2bf(float f) {
    union { float f; unsigned u; } a; a.f = f;
    unsigned r = a.u + 0x7fffu + ((a.u >> 16) & 1u);
    return (unsigned short)(r >> 16);
}

static __device__ __forceinline__ float bf2f(unsigned short s) {
    union { unsigned u; float f; } a; a.u = (unsigned)s << 16;
    return a.f;
}

// pack two f32 -> bf16x2 (round-half-up) in ~3 VALU ops
static __device__ __forceinline__ unsigned pkbf(float a, float b) {
    union { float f; unsigned u; } ua, ub; ua.f = a; ub.f = b;
    return __builtin_amdgcn_perm(ub.u + 0x8000u, ua.u + 0x8000u, 0x07060302u);
}

static __device__ __forceinline__ float ex2(float x) {
#if __has_builtin(__builtin_amdgcn_exp2f)
    return __builtin_amdgcn_exp2f(x);
#else
    return exp2f(x);
#endif
}

static __device__ __forceinline__ f32x4 mfma16(short8 a, short8 b, f32x4 c) {
    // D[row=quad*4+reg][col=lane&15]; A[row=lane&15][k=quad*8+j]; B[k=quad*8+j][col=lane&15]
    return __builtin_amdgcn_mfma_f32_16x16x32_bf16(a, b, c, 0, 0, 0);
}

// ---- staging helpers ----
static __device__ __forceinline__ void stage_w(const float* __restrict__ W,
                                               unsigned short* __restrict__ Wl, int t,
                                               float scale) {
#pragma unroll
    for (int i = 0; i < 16; i++) {
        int idx = i * 256 + t;
        int o = idx >> 5, c4 = (idx & 31) << 2;
        float4 v = *reinterpret_cast<const float4*>(W + o * C + c4);
        uint2 u;
        u.x = pkbf(v.x * scale, v.y * scale);
        u.y = pkbf(v.z * scale, v.w * scale);
        *reinterpret_cast<uint2*>(&Wl[o * 136 + c4]) = u;
    }
}

static __device__ __forceinline__ void stage_in(const float* __restrict__ In, int n0,
                                                unsigned short* __restrict__ Il, int t) {
#pragma unroll
    for (int i = 0; i < 8; i++) {
        int idx = i * 256 + t;
        int c = idx >> 4, n4 = (idx & 15) << 2;
        float4 v = *reinterpret_cast<const float4*>(In + (size_t)c * NSP + n0 + n4);
        Il[(n4 + 0) * 136 + c] = f2bf(v.x);
        Il[(n4 + 1) * 136 + c] = f2bf(v.y);
        Il[(n4 + 2) * 136 + c] = f2bf(v.z);
        Il[(n4 + 3) * 136 + c] = f2bf(v.w);
    }
}

// fused split-K combine + stage: Il[n][c] = (sum_k Op[k][jb][n][c]) / (sum_k Lp[k][jb][n])
static __device__ __forceinline__ void stage_att(const unsigned short* __restrict__ Op,
                                                 const float* __restrict__ Lp,
                                                 int jb, int n0,
                                                 unsigned short* __restrict__ Il, int t,
                                                 int nks) {
#pragma unroll
    for (int i = 0; i < 4; i++) {
        int idx = i * 256 + t;
        int n = idx >> 4, c8 = (idx & 15) << 3;
        float Ls = 0.0f;
        float o[8];
#pragma unroll
        for (int j = 0; j < 8; j++) o[j] = 0.0f;
        for (int k = 0; k < nks; k++) {
            size_t base = (size_t)(k * 4 + jb) * NSP + n0 + n;
            Ls += Lp[base];
            union { uint4 v; unsigned short s[8]; } u;
            u.v = *reinterpret_cast<const uint4*>(Op + base * C + c8);
#pragma unroll
            for (int j = 0; j < 8; j++) o[j] += bf2f(u.s[j]);
        }
        float inv = 1.0f / Ls;
        uint4 r;
        r.x = pkbf(o[0] * inv, o[1] * inv);
        r.y = pkbf(o[2] * inv, o[3] * inv);
        r.z = pkbf(o[4] * inv, o[5] * inv);
        r.w = pkbf(o[6] * inv, o[7] * inv);
        *reinterpret_cast<uint4*>(&Il[n * 136 + c8]) = r;
    }
}

// ======================= QKV projection =======================
// out = relu(W @ in + b).  Q,K stored [n][c] bf16 ; V stored [c][n] bf16.
// Q (kind 0) is pre-scaled by log2(e) so attention can use exp2 directly.
__global__ __launch_bounds__(256)
void qkv_kernel(const float* __restrict__ qs0, const float* __restrict__ qs1,
                const float* __restrict__ kv0, const float* __restrict__ kv1,
                const float* __restrict__ Wq, const float* __restrict__ Wk,
                const float* __restrict__ Wv,
                const float* __restrict__ bq, const float* __restrict__ bk,
                const float* __restrict__ bv,
                int layer_base,
                unsigned short* __restrict__ Qb, unsigned short* __restrict__ Kb,
                unsigned short* __restrict__ Vb)
{
    __shared__ __align__(16) unsigned short Wl[128 * 136];
    __shared__ __align__(16) unsigned short Il[64 * 136];
    const int t = threadIdx.x;
    const int ntile = blockIdx.x, kind = blockIdx.y, jb = blockIdx.z;
    const int job = jb >> 1, b = jb & 1, layer = layer_base + job;
    const float* src = (kind == 0) ? (job ? qs1 : qs0) : (job ? kv1 : kv0);
    const float* In = src + (size_t)b * C * NSP;
    const float* W = ((kind == 0) ? Wq : (kind == 1) ? Wk : Wv) + (size_t)layer * C * C;
    const float* bias = ((kind == 0) ? bq : (kind == 1) ? bk : bv) + layer * C;
    unsigned short* Out = ((kind == 0) ? Qb : (kind == 1) ? Kb : Vb) + (size_t)jb * NSP * C;
    const float scale = (kind == 0) ? LOG2E : 1.0f;
    const int n0 = ntile * 64;

    stage_w(W, Wl, t, scale);
    stage_in(In, n0, Il, t);
    __syncthreads();

    const int lane = t & 63, w = t >> 6, l15 = lane & 15, quad = lane >> 4;

    if (kind <= 1) {
        f32x4 acc[4][2];
#pragma unroll
        for (int nt = 0; nt < 4; nt++)
#pragma unroll
            for (int ot = 0; ot < 2; ot++)
#pragma unroll
                for (int r = 0; r < 4; r++) acc[nt][ot][r] = 0.0f;
#pragma unroll
        for (int ks = 0; ks < 4; ks++) {
            int co = ks * 32 + quad * 8;
            short8 b0 = *reinterpret_cast<const short8*>(&Wl[(w * 32 + l15) * 136 + co]);
            short8 b1 = *reinterpret_cast<const short8*>(&Wl[(w * 32 + 16 + l15) * 136 + co]);
#pragma unroll
            for (int nt = 0; nt < 4; nt++) {
                short8 a = *reinterpret_cast<const short8*>(&Il[(nt * 16 + l15) * 136 + co]);
                acc[nt][0] = mfma16(a, b0, acc[nt][0]);
                acc[nt][1] = mfma16(a, b1, acc[nt][1]);
            }
        }
        float bz0 = bias[w * 32 + l15] * scale;
        float bz1 = bias[w * 32 + 16 + l15] * scale;
#pragma unroll
        for (int nt = 0; nt < 4; nt++)
#pragma unroll
            for (int ot = 0; ot < 2; ot++)
#pragma unroll
                for (int r = 0; r < 4; r++) {
                    float v = fmaxf(acc[nt][ot][r] + (ot ? bz1 : bz0), 0.0f);
                    int n = n0 + nt * 16 + quad * 4 + r;
                    int o = w * 32 + ot * 16 + l15;
                    Out[(size_t)n * C + o] = f2bf(v);
                }
    } else {
        f32x4 acc[2][4];
#pragma unroll
        for (int ot = 0; ot < 2; ot++)
#pragma unroll
            for (int nt = 0; nt < 4; nt++)
#pragma unroll
                for (int r = 0; r < 4; r++) acc[ot][nt][r] = 0.0f;
#pragma unroll
        for (int ks = 0; ks < 4; ks++) {
            int co = ks * 32 + quad * 8;
            short8 a0 = *reinterpret_cast<const short8*>(&Wl[(w * 32 + l15) * 136 + co]);
            short8 a1 = *reinterpret_cast<const short8*>(&Wl[(w * 32 + 16 + l15) * 136 + co]);
#pragma unroll
            for (int nt = 0; nt < 4; nt++) {
                short8 bb = *reinterpret_cast<const short8*>(&Il[(nt * 16 + l15) * 136 + co]);
                acc[0][nt] = mfma16(a0, bb, acc[0][nt]);
                acc[1][nt] = mfma16(a1, bb, acc[1][nt]);
            }
        }
#pragma unroll
        for (int ot = 0; ot < 2; ot++)
#pragma unroll
            for (int r = 0; r < 4; r++) {
                int o = w * 32 + ot * 16 + quad * 4 + r;
                float bz = bias[o];
#pragma unroll
                for (int nt = 0; nt < 4; nt++) {
                    float v = fmaxf(acc[ot][nt][r] + bz, 0.0f);
                    Out[(size_t)o * NSP + n0 + nt * 16 + l15] = f2bf(v);
                }
            }
    }
}

// ======================= attention: P-pipelined flash, split-K over keys =======================
// No-max softmax (S >= 0, bounded; log2e folded into Q). Software pipeline: iteration blk
// computes QK_blk, then PV_{blk-1} (P from the previous iteration's LDS buffer -- its
// write latency is fully hidden), then exp_blk/P-write_blk (VALU co-issues with PV MFMAs).
// V staging lags K by one block so Vl holds V_{blk-1} when PV_{blk-1} runs.
__global__ __launch_bounds__(256)
void attn_kernel(const unsigned short* __restrict__ Qb, const unsigned short* __restrict__ Kb,
                 const unsigned short* __restrict__ Vb, unsigned short* __restrict__ Op,
                 float* __restrict__ Lp, int iters)
{
    __shared__ __align__(16) char smem[39424];
    unsigned short* Kl = (unsigned short*)smem;            // [32][136]   8704 B
    unsigned short* Vl = (unsigned short*)(smem + 8704);   // [128][40]  10240 B
    unsigned short* Pd = (unsigned short*)(smem + 18944);  // [2][4][32*40] 20480 B
    const int t = threadIdx.x, lane = t & 63, w = t >> 6;
    const int l15 = lane & 15, quad = lane >> 4;
    unsigned short* Pm[2] = { Pd + w * 1280, Pd + 5120 + w * 1280 };

    const int jb = blockIdx.y, kc = blockIdx.z;
    const int n0 = blockIdx.x * 128 + w * 32;
    const int m_begin = kc * iters * 32;
    const unsigned short* Q = Qb + (size_t)jb * NSP * C;
    const unsigned short* K = Kb + (size_t)jb * NSP * C;
    const unsigned short* V = Vb + (size_t)jb * NSP * C;  // [c][n]

    // Q fragments (B-operand), resident: [nt][ks]
    short8 qf[2][4];
#pragma unroll
    for (int nt = 0; nt < 2; nt++)
#pragma unroll
        for (int ks = 0; ks < 4; ks++)
            qf[nt][ks] = *reinterpret_cast<const short8*>(
                Q + (size_t)(n0 + nt * 16 + l15) * C + ks * 32 + quad * 8);

    f32x4 o_acc[8][2];
#pragma unroll
    for (int ct = 0; ct < 8; ct++)
#pragma unroll
        for (int nt = 0; nt < 2; nt++)
#pragma unroll
            for (int r = 0; r < 4; r++) o_acc[ct][nt][r] = 0.0f;
    float L[2] = {0.0f, 0.0f};

    // prologue: K_0 -> LDS; V_0 -> regs (written to LDS at end of body 0)
    uint4 kreg[2], vreg[2];
#pragma unroll
    for (int i = 0; i < 2; i++) {
        int idx = i * 256 + t;
        kreg[i] = *reinterpret_cast<const uint4*>(
            K + (size_t)(m_begin + (idx >> 4)) * C + ((idx & 15) << 3));
    }
#pragma unroll
    for (int i = 0; i < 2; i++) {
        int idx = i * 256 + t;
        *reinterpret_cast<uint4*>(&Kl[(idx >> 4) * 136 + ((idx & 15) << 3)]) = kreg[i];
    }
    __syncthreads();
#pragma unroll
    for (int i = 0; i < 2; i++) {
        int idx = i * 256 + t;
        vreg[i] = *reinterpret_cast<const uint4*>(
            V + (size_t)(idx >> 2) * NSP + m_begin + ((idx & 3) << 3));
    }

    for (int blk = 0; blk < iters; blk++) {
        // prefetch K_{blk+1} into regs (written to LDS at end of this body)
        if (blk + 1 < iters) {
            int mb = m_begin + (blk + 1) * 32;
#pragma unroll
            for (int i = 0; i < 2; i++) {
                int idx = i * 256 + t;
                kreg[i] = *reinterpret_cast<const uint4*>(
                    K + (size_t)(mb + (idx >> 4)) * C + ((idx & 15) << 3));
            }
        }
        // ---- QK_blk: S^T[m][n] from Kl (holds K_blk) ----
        f32x4 s[2][2];
#pragma unroll
        for (int mt = 0; mt < 2; mt++)
#pragma unroll
            for (int nt = 0; nt < 2; nt++)
#pragma unroll
                for (int r = 0; r < 4; r++) s[mt][nt][r] = 0.0f;
#pragma unroll
        for (int ks = 0; ks < 4; ks++) {
            int co = ks * 32 + quad * 8;
            short8 k0 = *reinterpret_cast<const short8*>(&Kl[l15 * 136 + co]);
            short8 k1 = *reinterpret_cast<const short8*>(&Kl[(16 + l15) * 136 + co]);
            s[0][0] = mfma16(k0, qf[0][ks], s[0][0]);
            s[0][1] = mfma16(k0, qf[1][ks], s[0][1]);
            s[1][0] = mfma16(k1, qf[0][ks], s[1][0]);
            s[1][1] = mfma16(k1, qf[1][ks], s[1][1]);
        }
        // ---- PV_{blk-1}: P from Pm[(blk-1)&1], V_{blk-1} from Vl ----
        if (blk > 0) {
            const unsigned short* Pr = Pm[(blk - 1) & 1];
            short8 pf0 = *reinterpret_cast<const short8*>(&Pr[l15 * 40 + quad * 8]);
            short8 pf1 = *reinterpret_cast<const short8*>(&Pr[(16 + l15) * 40 + quad * 8]);
#pragma unroll
            for (int ct = 0; ct < 8; ct++) {
                short8 vf = *reinterpret_cast<const short8*>(&Vl[(ct * 16 + l15) * 40 + quad * 8]);
                o_acc[ct][0] = mfma16(vf, pf0, o_acc[ct][0]);
                o_acc[ct][1] = mfma16(vf, pf1, o_acc[ct][1]);
            }
        }
        // ---- exp_blk (VALU; co-issues with PV MFMAs) + pack + write Pm[blk&1] ----
        unsigned short* Pc = Pm[blk & 1];
#pragma unroll
        for (int nt = 0; nt < 2; nt++) {
            float pv[2][4];
            float ls = 0.0f;
#pragma unroll
            for (int mt = 0; mt < 2; mt++)
#pragma unroll
                for (int r = 0; r < 4; r++) {
                    pv[mt][r] = ex2(s[mt][nt][r]);
                    ls += pv[mt][r];
                }
            L[nt] += ls;
#pragma unroll
            for (int mt = 0; mt < 2; mt++) {
                uint2 u;
                u.x = pkbf(pv[mt][0], pv[mt][1]);
                u.y = pkbf(pv[mt][2], pv[mt][3]);
                *reinterpret_cast<uint2*>(&Pc[(nt * 16 + l15) * 40 + mt * 16 + quad * 4]) = u;
            }
        }
        __syncthreads();  // all waves done reading Kl (QK_blk) and Vl (PV_{blk-1})
        if (blk + 1 < iters) {
#pragma unroll
            for (int i = 0; i < 2; i++) {
                int idx = i * 256 + t;
                *reinterpret_cast<uint4*>(&Kl[(idx >> 4) * 136 + ((idx & 15) << 3)]) = kreg[i];
            }
        }
#pragma unroll
        for (int i = 0; i < 2; i++) {  // V_blk -> Vl (consumed next iteration)
            int idx = i * 256 + t;
            *reinterpret_cast<uint4*>(&Vl[(idx >> 2) * 40 + ((idx & 3) << 3)]) = vreg[i];
        }
        __syncthreads();
        if (blk + 1 < iters) {  // V_{blk+1} -> regs
            int mb = m_begin + (blk + 1) * 32;
#pragma unroll
            for (int i = 0; i < 2; i++) {
                int idx = i * 256 + t;
                vreg[i] = *reinterpret_cast<const uint4*>(
                    V + (size_t)(idx >> 2) * NSP + mb + ((idx & 3) << 3));
            }
        }
    }

    // drain: PV_{iters-1} (Vl holds V_{iters-1})
    {
        const unsigned short* Pr = Pm[(iters - 1) & 1];
        short8 pf0 = *reinterpret_cast<const short8*>(&Pr[l15 * 40 + quad * 8]);
        short8 pf1 = *reinterpret_cast<const short8*>(&Pr[(16 + l15) * 40 + quad * 8]);
#pragma unroll
        for (int ct = 0; ct < 8; ct++) {
            short8 vf = *reinterpret_cast<const short8*>(&Vl[(ct * 16 + l15) * 40 + quad * 8]);
            o_acc[ct][0] = mfma16(vf, pf0, o_acc[ct][0]);
            o_acc[ct][1] = mfma16(vf, pf1, o_acc[ct][1]);
        }
    }

    // epilogue: L reduce + coalesced partial-O store via wave-private LDS transpose
    const size_t kjb = (size_t)(kc * 4 + jb);
#pragma unroll
    for (int nt = 0; nt < 2; nt++) {
        float Lv = L[nt];
        Lv += __shfl_xor(Lv, 16);
        Lv += __shfl_xor(Lv, 32);
        if (quad == 0) Lp[kjb * NSP + n0 + nt * 16 + l15] = Lv;
    }
    __syncthreads();  // done with Kl/Vl everywhere; safe to alias for transpose
    unsigned short* Ow = (unsigned short*)smem + w * 2176;  // 16x136 per wave
    unsigned short* Ob = Op + kjb * NSP * C;  // [n][c]
#pragma unroll
    for (int nt = 0; nt < 2; nt++) {
#pragma unroll
        for (int ct = 0; ct < 8; ct++) {
            uint2 u;
            u.x = pkbf(o_acc[ct][nt][0], o_acc[ct][nt][1]);
            u.y = pkbf(o_acc[ct][nt][2], o_acc[ct][nt][3]);
            *reinterpret_cast<uint2*>(&Ow[l15 * 136 + ct * 16 + quad * 4]) = u;
        }
#pragma unroll
        for (int i = 0; i < 4; i++) {
            int nl = i * 4 + quad;
            uint4 v = *reinterpret_cast<const uint4*>(&Ow[nl * 136 + l15 * 8]);
            *reinterpret_cast<uint4*>(Ob + (size_t)(n0 + nt * 16 + nl) * C + l15 * 8) = v;
        }
    }
}

// ======================= output projection + residual (pass 1), fused combine =======================
__global__ __launch_bounds__(256)
void proj_kernel(const unsigned short* __restrict__ Op, const float* __restrict__ Lp, int nks,
                 const float* __restrict__ Wo, const float* __restrict__ bo, int layer_base,
                 const float* __restrict__ res0, const float* __restrict__ res1,
                 float* __restrict__ out0, float* __restrict__ out1)
{
    __shared__ __align__(16) unsigned short Wl[128 * 136];
    __shared__ __align__(16) unsigned short Il[64 * 136];
    const int t = threadIdx.x;
    const int ntile = blockIdx.x, jb = blockIdx.y;
    const int job = jb >> 1, b = jb & 1, layer = layer_base + job;
    const float* bias = bo + layer * C;
    const float* res = (job ? res1 : res0) + (size_t)b * C * NSP;
    float* out = (job ? out1 : out0) + (size_t)b * C * NSP;
    const int n0 = ntile * 64;

    stage_w(Wo + (size_t)layer * C * C, Wl, t, 1.0f);
    stage_att(Op, Lp, jb, n0, Il, t, nks);
    __syncthreads();

    const int lane = t & 63, w = t >> 6, l15 = lane & 15, quad = lane >> 4;
    f32x4 acc[2][4];
#pragma unroll
    for (int ot = 0; ot < 2; ot++)
#pragma unroll
        for (int nt = 0; nt < 4; nt++)
#pragma unroll
            for (int r = 0; r < 4; r++) acc[ot][nt][r] = 0.0f;
#pragma unroll
    for (int ks = 0; ks < 4; ks++) {
        int co = ks * 32 + quad * 8;
        short8 a0 = *reinterpret_cast<const short8*>(&Wl[(w * 32 + l15) * 136 + co]);
        short8 a1 = *reinterpret_cast<const short8*>(&Wl[(w * 32 + 16 + l15) * 136 + co]);
#pragma unroll
        for (int nt = 0; nt < 4; nt++) {
            short8 bb = *reinterpret_cast<const short8*>(&Il[(nt * 16 + l15) * 136 + co]);
            acc[0][nt] = mfma16(a0, bb, acc[0][nt]);
            acc[1][nt] = mfma16(a1, bb, acc[1][nt]);
        }
    }
#pragma unroll
    for (int ot = 0; ot < 2; ot++)
#pragma unroll
        for (int r = 0; r < 4; r++) {
            int o = w * 32 + ot * 16 + quad * 4 + r;
            float bz = bias[o];
#pragma unroll
            for (int nt = 0; nt < 4; nt++) {
                int n = n0 + nt * 16 + l15;
                float v = fmaxf(acc[ot][nt][r] + bz, 0.0f) + res[(size_t)o * NSP + n];
                out[(size_t)o * NSP + n] = v;
            }
        }
}

// ======================= final: both jobs summed into d_out, fused combine =======================
__global__ __launch_bounds__(256)
void final_kernel(const unsigned short* __restrict__ Op, const float* __restrict__ Lp, int nks,
                  const float* __restrict__ Wo, const float* __restrict__ bo,
                  const float* __restrict__ fuse0, const float* __restrict__ fuse1,
                  float* __restrict__ out)
{
    __shared__ __align__(16) unsigned short Wl[128 * 136];
    __shared__ __align__(16) unsigned short Il[64 * 136];
    const int t = threadIdx.x;
    const int ntile = blockIdx.x, b = blockIdx.y;
    const int n0 = ntile * 64;
    const int lane = t & 63, w = t >> 6, l15 = lane & 15, quad = lane >> 4;

    float tot[2][4][4];
#pragma unroll
    for (int ot = 0; ot < 2; ot++)
#pragma unroll
        for (int nt = 0; nt < 4; nt++)
#pragma unroll
            for (int r = 0; r < 4; r++) tot[ot][nt][r] = 0.0f;

    for (int j = 0; j < 2; j++) {
        if (j) __syncthreads();
        int layer = 2 + j;
        stage_w(Wo + (size_t)layer * C * C, Wl, t, 1.0f);
        stage_att(Op, Lp, j * 2 + b, n0, Il, t, nks);
        __syncthreads();

        f32x4 acc[2][4];
#pragma unroll
        for (int ot = 0; ot < 2; ot++)
#pragma unroll
            for (int nt = 0; nt < 4; nt++)
#pragma unroll
                for (int r = 0; r < 4; r++) acc[ot][nt][r] = 0.0f;
#pragma unroll
        for (int ks = 0; ks < 4; ks++) {
            int co = ks * 32 + quad * 8;
            short8 a0 = *reinterpret_cast<const short8*>(&Wl[(w * 32 + l15) * 136 + co]);
            short8 a1 = *reinterpret_cast<const short8*>(&Wl[(w * 32 + 16 + l15) * 136 + co]);
#pragma unroll
            for (int nt = 0; nt < 4; nt++) {
                short8 bb = *reinterpret_cast<const short8*>(&Il[(nt * 16 + l15) * 136 + co]);
                acc[0][nt] = mfma16(a0, bb, acc[0][nt]);
                acc[1][nt] = mfma16(a1, bb, acc[1][nt]);
            }
        }
        const float* bias = bo + layer * C;
        const float* fuse = (j ? fuse1 : fuse0) + (size_t)b * C * NSP;
#pragma unroll
        for (int ot = 0; ot < 2; ot++)
#pragma unroll
            for (int r = 0; r < 4; r++) {
                int o = w * 32 + ot * 16 + quad * 4 + r;
                float bz = bias[o];
#pragma unroll
                for (int nt = 0; nt < 4; nt++) {
                    int n = n0 + nt * 16 + l15;
                    tot[ot][nt][r] += fmaxf(acc[ot][nt][r] + bz, 0.0f) + fuse[(size_t)o * NSP + n];
                }
            }
    }
#pragma unroll
    for (int ot = 0; ot < 2; ot++)
#pragma unroll
        for (int r = 0; r < 4; r++) {
            int o = w * 32 + ot * 16 + quad * 4 + r;
#pragma unroll
            for (int nt = 0; nt < 4; nt++) {
                int n = n0 + nt * 16 + l15;
                out[(size_t)b * C * NSP + (size_t)o * NSP + n] = tot[ot][nt][r];
            }
        }
}

extern "C" void kernel_launch(void* const* d_in, const int* in_sizes, int n_in,
                              void* d_out, int out_size, void* d_ws, size_t ws_size,
                              hipStream_t stream)
{
    (void)in_sizes; (void)n_in; (void)out_size;
    const float* x  = (const float*)d_in[0];
    const float* y  = (const float*)d_in[1];
    const float* Wq = (const float*)d_in[2];
    const float* bq = (const float*)d_in[3];
    const float* Wk = (const float*)d_in[4];
    const float* bk = (const float*)d_in[5];
    const float* Wv = (const float*)d_in[6];
    const float* bv = (const float*)d_in[7];
    const float* Wo = (const float*)d_in[8];
    const float* bo = (const float*)d_in[9];
    float* out = (float*)d_out;
    char* ws = (char*)d_ws;

    // split-K factor from available workspace (constant per process)
    // need(ks) = 12M (QKV) + ks*4M (Op) + ks*64K (Lp) + 8M (fuse)
    int ks = (ws_size >= 55050240u) ? 8 : (ws_size >= 38010880u) ? 4 : 2;
    int iters = 128 / ks;

    unsigned short* Qb = (unsigned short*)(ws);               // 4 MB [jb][n][c]
    unsigned short* Kb = (unsigned short*)(ws + (4u << 20));  // 4 MB [jb][n][c]
    unsigned short* Vb = (unsigned short*)(ws + (8u << 20));  // 4 MB [jb][c][n]
    unsigned short* Op = (unsigned short*)(ws + (12u << 20)); // ks*4 MB [k][jb][n][c] bf16
    size_t op_bytes = (size_t)ks * 4 * NSP * C * 2;
    float* Lp = (float*)(ws + (12u << 20) + op_bytes);        // ks*64 KB [k*4+jb][n]
    float* fuse0 = Lp + (size_t)ks * 4 * NSP;                 // 4 MB [b][c][n] fp32
    float* fuse1 = fuse0 + (size_t)2 * C * NSP;               // 4 MB

    // pass 1: L0 (Q from x, KV from y), L1 (Q from y, KV from x)
    qkv_kernel<<<dim3(64, 3, 4), 256, 0, stream>>>(x, y, y, x, Wq, Wk, Wv, bq, bk, bv, 0,
                                                   Qb, Kb, Vb);
    attn_kernel<<<dim3(32, 4, ks), 256, 0, stream>>>(Qb, Kb, Vb, Op, Lp, iters);
    proj_kernel<<<dim3(64, 4), 256, 0, stream>>>(Op, Lp, ks, Wo, bo, 0, x, y, fuse0, fuse1);

    // pass 2: L2 (all from fuse_xy), L3 (all from fuse_yz)
    qkv_kernel<<<dim3(64, 3, 4), 256, 0, stream>>>(fuse0, fuse1, fuse0, fuse1, Wq, Wk, Wv,
                                                   bq, bk, bv, 2, Qb, Kb, Vb);
    attn_kernel<<<dim3(32, 4, ks), 256, 0, stream>>>(Qb, Kb, Vb, Op, Lp, iters);
    final_kernel<<<dim3(64, 2), 256, 0, stream>>>(Op, Lp, ks, Wo, bo, fuse0, fuse1, out);
}